// Round 6
// baseline (340.971 us; speedup 1.0000x reference)
//
#include <hip/hip_runtime.h>
#include <hip/hip_bf16.h>
#include <hip/hip_cooperative_groups.h>

namespace cg = cooperative_groups;

#define IN_CH 128
#define HID 64
#define NEG_SLOPE 0.2f
#define BSH 8            // bucket = dst >> 8  (256 dsts per bucket)
#define CAP 10240        // per-bucket capacity (mean 8184, ~20-sigma slack)

typedef __attribute__((ext_vector_type(8))) short short8;   // bf16x8 frag (4 VGPRs)
typedef __attribute__((ext_vector_type(4))) float floatx4;  // fp32x4 acc
typedef __attribute__((ext_vector_type(2))) float f32x2;    // packed fma pair

__device__ inline short bfr(float f) {   // fp32 -> bf16 bits, round-nearest-even
    unsigned u = __float_as_uint(f);
    u += 0x7fffu + ((u >> 16) & 1u);
    return (short)(u >> 16);
}

// ---------------------------------------------------------------------------
// h = x @ W via mfma_f32_16x16x32_bf16, with W-fragment prep FUSED: each
// block stages W (32 KB) into pad-65 LDS (write: 4-float runs, free; read:
// bank = ((k0+j)+n)%32, exactly 2-way across 64 lanes = free [m136]) and
// builds its bf16 B-fragments locally. Block 0 also zeroes g_cursor.
// Removes the k_prep dispatch + wfrag global round-trip.
// C-layout: col = lane&15, row = quad*4 + reg  [m89].
// ---------------------------------------------------------------------------
__global__ __launch_bounds__(256) void k_gemm(
    const float* __restrict__ x, const float* __restrict__ W,
    const float* __restrict__ att_src, const float* __restrict__ att_dst,
    short* __restrict__ h, float* __restrict__ a_src,
    float* __restrict__ a_dst, int* __restrict__ g_cursor, int N)
{
    __shared__ float wlds[IN_CH * 65];   // pad 65: conflict-free column reads

    const int t = threadIdx.x;
    const int lane = t & 63;
    const int wv = t >> 6;
    const int l15 = lane & 15;
    const int quad = lane >> 4;

    if (blockIdx.x == 0) { g_cursor[t] = 0; g_cursor[t + 256] = 0; }

    // stage W: 2048 float4 loads, write into padded rows (4-float runs)
#pragma unroll
    for (int r = 0; r < 8; ++r) {
        const int idx4 = r * 256 + t;
        const float4 w4 = ((const float4*)W)[idx4];
        const int fi = idx4 * 4;
        float* dst = &wlds[(fi >> 6) * 65 + (fi & 63)];
        dst[0] = w4.x; dst[1] = w4.y; dst[2] = w4.z; dst[3] = w4.w;
    }
    __syncthreads();

    // build B fragments: frag f = kt*4+nt; lane holds B[k0+j][n]
    short8 bf[16];
#pragma unroll
    for (int f = 0; f < 16; ++f) {
        const int kt = f >> 2, nt = f & 3;
        const int k0 = kt * 32 + quad * 8;
        const int n = nt * 16 + l15;
        short8 a;
#pragma unroll
        for (int j = 0; j < 8; ++j) a[j] = bfr(wlds[(k0 + j) * 65 + n]);
        bf[f] = a;
    }

    float as4[4], ad4[4];
#pragma unroll
    for (int nt = 0; nt < 4; ++nt) {
        as4[nt] = att_src[nt * 16 + l15];
        ad4[nt] = att_dst[nt * 16 + l15];
    }

    const int rowbase = blockIdx.x * 128 + wv * 32;

#pragma unroll
    for (int mt = 0; mt < 2; ++mt) {
        const int m0 = rowbase + mt * 16;
        const int rowa = m0 + l15;
        const int rowc = rowa < N ? rowa : N - 1;   // clamp loads
        const float* xp = x + (size_t)rowc * IN_CH + quad * 8;

        short8 af[4];
#pragma unroll
        for (int kt = 0; kt < 4; ++kt) {
            float4 p0 = *(const float4*)(xp + kt * 32);
            float4 p1 = *(const float4*)(xp + kt * 32 + 4);
            short8 a;
            a[0] = bfr(p0.x); a[1] = bfr(p0.y); a[2] = bfr(p0.z); a[3] = bfr(p0.w);
            a[4] = bfr(p1.x); a[5] = bfr(p1.y); a[6] = bfr(p1.z); a[7] = bfr(p1.w);
            af[kt] = a;
        }

        floatx4 acc[4];
#pragma unroll
        for (int nt = 0; nt < 4; ++nt) acc[nt] = (floatx4){0.f, 0.f, 0.f, 0.f};
#pragma unroll
        for (int kt = 0; kt < 4; ++kt)
#pragma unroll
            for (int nt = 0; nt < 4; ++nt)
                acc[nt] = __builtin_amdgcn_mfma_f32_16x16x32_bf16(
                    af[kt], bf[kt * 4 + nt], acc[nt], 0, 0, 0);

        // epilogue: rows m0 + quad*4 + r
#pragma unroll
        for (int r = 0; r < 4; ++r) {
            const int row = m0 + quad * 4 + r;
            const bool ok = row < N;
            if (ok) {
#pragma unroll
                for (int nt = 0; nt < 4; ++nt)
                    h[(size_t)row * HID + nt * 16 + l15] = bfr(acc[nt][r]);
            }
            float ps = acc[0][r] * as4[0] + acc[1][r] * as4[1] +
                       acc[2][r] * as4[2] + acc[3][r] * as4[3];
            float pd = acc[0][r] * ad4[0] + acc[1][r] * ad4[1] +
                       acc[2][r] * ad4[2] + acc[3][r] * ad4[3];
#pragma unroll
            for (int m2 = 1; m2 < 16; m2 <<= 1) {
                ps += __shfl_xor(ps, m2, 64);
                pd += __shfl_xor(pd, m2, 64);
            }
            if (ok && l15 == 0) { a_src[row] = ps; a_dst[row] = pd; }
        }
    }
}

// ---------------------------------------------------------------------------
// Cooperative sort: binB + binC fused via grid.sync(). 391 blocks x 512 thr;
// __launch_bounds__(512,4) caps VGPR<=128 -> >=2 blocks/CU -> capacity 512
// blocks >= 391 (cooperative launch guaranteed to fit).
// Phase 1: per-block chunk of edges -> LDS hist rank -> reserve -> scatter
// packed pairs (s | (dst&255)<<17) into per-bucket windows.
// Phase 2: block b finalizes bucket b (two-pass: hist, scan, scatter csr).
// ---------------------------------------------------------------------------
__global__ __launch_bounds__(512, 4) void k_sort(
    const int* __restrict__ ei, int* __restrict__ g_cursor,
    int* __restrict__ pairs, int* __restrict__ row_start,
    int* __restrict__ cnt, int* __restrict__ csr_src, int E, int N, int nb)
{
    __shared__ int hist[512];
    __shared__ int base[512];
    __shared__ int cur[256];
    __shared__ int sbase;

    const int t = threadIdx.x;
    const int b = blockIdx.x;

    // ---- phase 1: bin ----
    hist[t] = 0;
    __syncthreads();

    const int E4 = E >> 2;
    const int C4 = (E4 + nb - 1) / nb;        // int4 chunk per block
    const int q0 = b * C4;
    const int q1 = min(q0 + C4, E4);

    int s[16], d[16], l[16];
#pragma unroll
    for (int k = 0; k < 4; ++k) {
        const int q = q0 + k * 512 + t;
        int4 sv = make_int4(0, 0, 0, 0);
        int4 dv = make_int4(-1, -1, -1, -1);
        if (q < q1) { sv = ((const int4*)ei)[q]; dv = ((const int4*)(ei + E))[q]; }
        s[4 * k + 0] = sv.x; s[4 * k + 1] = sv.y; s[4 * k + 2] = sv.z; s[4 * k + 3] = sv.w;
        d[4 * k + 0] = dv.x; d[4 * k + 1] = dv.y; d[4 * k + 2] = dv.z; d[4 * k + 3] = dv.w;
    }
#pragma unroll
    for (int i = 0; i < 16; ++i)
        if (d[i] >= 0) l[i] = atomicAdd(&hist[d[i] >> BSH], 1);
    __syncthreads();

    if (t < nb) base[t] = atomicAdd(&g_cursor[t], hist[t]);
    __syncthreads();

#pragma unroll
    for (int i = 0; i < 16; ++i) {
        if (d[i] < 0) continue;
        const int bb = d[i] >> BSH;
        const int pos = base[bb] + l[i];
        if (pos < CAP)
            pairs[bb * CAP + pos] = s[i] | ((d[i] & 255) << 17);
    }

    cg::this_grid().sync();

    // ---- phase 2: finalize bucket b ----
    int m = g_cursor[b];
    if (m > CAP) m = CAP;
    const int* pb = pairs + b * CAP;

    // exclusive bucket-base scan over g_cursor[0..nb)
    const int bv = (t < nb) ? g_cursor[t] : 0;
    hist[t] = bv;
    __syncthreads();
    for (int off = 1; off < 512; off <<= 1) {
        int u = (t >= off) ? hist[t - off] : 0;
        __syncthreads();
        hist[t] += u;
        __syncthreads();
    }
    if (t == b) sbase = hist[t] - bv;
    if (t < 256) base[t] = 0;                 // base reused as h0
    __syncthreads();
    const int basec = sbase;

    for (int i = t; i < m; i += 512)
        atomicAdd(&base[pb[i] >> 17], 1);     // unreturned -> cheap
    __syncthreads();

    if (t < 256) hist[t] = base[t];
    __syncthreads();
    for (int off = 1; off < 256; off <<= 1) {
        int u = (t >= off && t < 256) ? hist[t - off] : 0;
        __syncthreads();
        if (t < 256) hist[t] += u;
        __syncthreads();
    }
    if (t < 256) {
        const int e0 = hist[t] - base[t];
        cur[t] = basec + e0;
        const int dd = (b << BSH) + t;
        if (dd < N) { row_start[dd] = basec + e0; cnt[dd] = base[t]; }
    }
    __syncthreads();

    for (int i = t; i < m; i += 512) {
        const int p = pb[i];
        const int pos = atomicAdd(&cur[p >> 17], 1);
        csr_src[pos] = p & 0x1FFFF;
    }
}

// ---------------------------------------------------------------------------
// Aggregation: two dsts per wave, interleaved -> 8 gather loads in flight,
// shfl-broadcast of (s,e) from the batch lanes. UNCHANGED (control).
// ---------------------------------------------------------------------------
__global__ __launch_bounds__(256) void k_agg(
    const __hip_bfloat16* __restrict__ h, const float* __restrict__ a_src,
    const float* __restrict__ a_dst, const float* __restrict__ bias,
    const int* __restrict__ row_start, const int* __restrict__ cnt,
    const int* __restrict__ csr_src,
    float* __restrict__ out, float2* __restrict__ adi, int N)
{
    __shared__ float red[4][2][576];   // [wave][dst][ch*9+q], pad 9

    const int wave = threadIdx.x >> 6;
    const int lane = threadIdx.x & 63;
    const int d0 = blockIdx.x * 8 + wave * 2;
    if (d0 >= N) return;
    const int d1 = d0 + 1;
    const bool has1 = d1 < N;

    const int q  = lane >> 3;   // row slot within group of 8
    const int i8 = lane & 7;    // 16-B chunk of the 128-B row

    const float2 ad2 = *(const float2*)(a_dst + d0);   // d0 even
    const float ad0 = ad2.x;
    const float ad1 = ad2.y;
    const int2 cn2 = *(const int2*)(cnt + d0);
    const int n0 = cn2.x;
    const int n1 = has1 ? cn2.y : 0;
    const int st0 = row_start[d0];
    const int en0 = st0 + n0;
    const int st1 = en0;                 // CSR globally contiguous
    const int en1 = st1 + n1;

    const uint4* h4 = (const uint4*)h;

    float ps0 = 0.f, ps1 = 0.f;
    f32x2 ac0[4], ac1[4];
#pragma unroll
    for (int c = 0; c < 4; ++c) {
        ac0[c] = (f32x2){0.f, 0.f};
        ac1[c] = (f32x2){0.f, 0.f};
    }

    const int nbt0 = (n0 + 63) >> 6;
    const int nbt1 = (n1 + 63) >> 6;
    const int nbm = nbt0 > nbt1 ? nbt0 : nbt1;

    int b0 = st0, b1 = st1;
    for (int it = 0; it < nbm; ++it, b0 += 64, b1 += 64) {
        int s0v = 0, s1v = 0;
        float e0 = 0.f, e1 = 0.f;
        const int idx0 = b0 + lane;
        if (it < nbt0 && idx0 < en0) {
            s0v = csr_src[idx0];
            float v = a_src[s0v] + ad0;
            v = v > 0.f ? v : NEG_SLOPE * v;
            e0 = __expf(v);
            ps0 += e0;
        }
        const int idx1 = b1 + lane;
        if (it < nbt1 && idx1 < en1) {
            s1v = csr_src[idx1];
            float v = a_src[s1v] + ad1;
            v = v > 0.f ? v : NEG_SLOPE * v;
            e1 = __expf(v);
            ps1 += e1;
        }
        const int m0 = (it < nbt0) ? min(64, en0 - b0) : 0;
        const int m1 = (it < nbt1) ? min(64, en1 - b1) : 0;
        const int mm = m0 > m1 ? m0 : m1;
#pragma unroll 4
        for (int j = 0; j < mm; j += 8) {
            const int jq = j + q;
            const int sj0 = __shfl(s0v, jq, 64);    // inactive slots: s=0,e=0
            const float ej0 = __shfl(e0, jq, 64);   // -> harmless row-0 load
            const int sj1 = __shfl(s1v, jq, 64);
            const float ej1 = __shfl(e1, jq, 64);
            uint4 u0 = h4[(size_t)sj0 * 8 + i8];
            uint4 u1 = h4[(size_t)sj1 * 8 + i8];
            f32x2 ev0; ev0[0] = ej0; ev0[1] = ej0;
            f32x2 ev1; ev1[0] = ej1; ev1[1] = ej1;
            f32x2 c;
            c[0] = __uint_as_float(u0.x << 16);
            c[1] = __uint_as_float(u0.x & 0xffff0000u);
            ac0[0] = __builtin_elementwise_fma(ev0, c, ac0[0]);
            c[0] = __uint_as_float(u0.y << 16);
            c[1] = __uint_as_float(u0.y & 0xffff0000u);
            ac0[1] = __builtin_elementwise_fma(ev0, c, ac0[1]);
            c[0] = __uint_as_float(u0.z << 16);
            c[1] = __uint_as_float(u0.z & 0xffff0000u);
            ac0[2] = __builtin_elementwise_fma(ev0, c, ac0[2]);
            c[0] = __uint_as_float(u0.w << 16);
            c[1] = __uint_as_float(u0.w & 0xffff0000u);
            ac0[3] = __builtin_elementwise_fma(ev0, c, ac0[3]);
            c[0] = __uint_as_float(u1.x << 16);
            c[1] = __uint_as_float(u1.x & 0xffff0000u);
            ac1[0] = __builtin_elementwise_fma(ev1, c, ac1[0]);
            c[0] = __uint_as_float(u1.y << 16);
            c[1] = __uint_as_float(u1.y & 0xffff0000u);
            ac1[1] = __builtin_elementwise_fma(ev1, c, ac1[1]);
            c[0] = __uint_as_float(u1.z << 16);
            c[1] = __uint_as_float(u1.z & 0xffff0000u);
            ac1[2] = __builtin_elementwise_fma(ev1, c, ac1[2]);
            c[0] = __uint_as_float(u1.w << 16);
            c[1] = __uint_as_float(u1.w & 0xffff0000u);
            ac1[3] = __builtin_elementwise_fma(ev1, c, ac1[3]);
        }
    }

    // stash partials to LDS, channel-major pad-9: addr = ch*9 + q with
    // ch = i8*8 + c. Write banks = bit-swap(lane) perm -> 2-way (free).
    float* r0 = &red[wave][0][0];
    float* r1 = &red[wave][1][0];
#pragma unroll
    for (int p = 0; p < 4; ++p) {
        r0[(i8 * 8 + 2 * p) * 9 + q]     = ac0[p][0];
        r0[(i8 * 8 + 2 * p + 1) * 9 + q] = ac0[p][1];
        r1[(i8 * 8 + 2 * p) * 9 + q]     = ac1[p][0];
        r1[(i8 * 8 + 2 * p + 1) * 9 + q] = ac1[p][1];
    }

    // psum reduce (overlaps LDS settle)
#pragma unroll
    for (int m2 = 32; m2 > 0; m2 >>= 1) {
        ps0 += __shfl_xor(ps0, m2, 64);
        ps1 += __shfl_xor(ps1, m2, 64);
    }

    const float2 asd = *(const float2*)(a_src + d0);
    float vs0 = asd.x + ad0;
    vs0 = vs0 > 0.f ? vs0 : NEG_SLOPE * vs0;
    const float es0 = __expf(vs0);
    const float inv0 = 1.f / (ps0 + es0);
    float es1 = 0.f, inv1 = 0.f;
    if (has1) {
        float vs1 = asd.y + ad1;
        vs1 = vs1 > 0.f ? vs1 : NEG_SLOPE * vs1;
        es1 = __expf(vs1);
        inv1 = 1.f / (ps1 + es1);
    }
    if (lane == 0) {
        adi[d0] = make_float2(ad0, inv0);
        if (has1) adi[d1] = make_float2(ad1, inv1);
    }

    // lane t owns channel ch == lane: sum its 8 q-partials
    float s0 = 0.f, s1 = 0.f;
#pragma unroll
    for (int qq = 0; qq < 8; ++qq) {
        s0 += r0[lane * 9 + qq];
        s1 += r1[lane * 9 + qq];
    }

    const ushort* hu = (const ushort*)h;
    const float bi = bias[lane];
    float hs0 = __uint_as_float(((unsigned)hu[(size_t)d0 * HID + lane]) << 16);
    out[(size_t)d0 * HID + lane] = fmaf(es0, hs0, s0) * inv0 + bi;
    if (has1) {
        float hs1 = __uint_as_float(((unsigned)hu[(size_t)d1 * HID + lane]) << 16);
        out[(size_t)d1 * HID + lane] = fmaf(es1, hs1, s1) * inv1 + bi;
    }
}

// ---------------------------------------------------------------------------
// edge-order alpha, vectorized 4-wide: int4 index loads, float4 stores.
// Self-loop entries (alpha[E..E+N)) handled as the tail thread range.
// ---------------------------------------------------------------------------
__global__ void k_alpha(const int* __restrict__ ei,
                        const float* __restrict__ a_src,
                        const float2* __restrict__ adi,
                        float* __restrict__ out_alpha, int E, int N)
{
    const int E4 = E >> 2;
    const int i = blockIdx.x * 256 + threadIdx.x;
    if (i < E4) {
        const int4 sv = ((const int4*)ei)[i];
        const int4 dv = ((const int4*)(ei + E))[i];
        float4 o;
        {
            const float2 av = adi[dv.x];
            float v = a_src[sv.x] + av.x;
            v = v > 0.f ? v : NEG_SLOPE * v;
            o.x = __expf(v) * av.y;
        }
        {
            const float2 av = adi[dv.y];
            float v = a_src[sv.y] + av.x;
            v = v > 0.f ? v : NEG_SLOPE * v;
            o.y = __expf(v) * av.y;
        }
        {
            const float2 av = adi[dv.z];
            float v = a_src[sv.z] + av.x;
            v = v > 0.f ? v : NEG_SLOPE * v;
            o.z = __expf(v) * av.y;
        }
        {
            const float2 av = adi[dv.w];
            float v = a_src[sv.w] + av.x;
            v = v > 0.f ? v : NEG_SLOPE * v;
            o.w = __expf(v) * av.y;
        }
        ((float4*)out_alpha)[i] = o;
    } else {
        const int j = i - E4;
        if (j < N) {
            const float2 av = adi[j];
            float v = a_src[j] + av.x;
            v = v > 0.f ? v : NEG_SLOPE * v;
            out_alpha[E + j] = __expf(v) * av.y;
        }
    }
}

// ---------------------------------------------------------------------------
extern "C" void kernel_launch(void* const* d_in, const int* in_sizes, int n_in,
                              void* d_out, int out_size, void* d_ws, size_t ws_size,
                              hipStream_t stream)
{
    (void)n_in; (void)out_size; (void)ws_size;
    const float* x       = (const float*)d_in[0];
    const int*   ei      = (const int*)d_in[1];
    const float* W       = (const float*)d_in[2];
    const float* att_src = (const float*)d_in[3];
    const float* att_dst = (const float*)d_in[4];
    const float* bias    = (const float*)d_in[5];

    const int N = in_sizes[0] / IN_CH;   // 100000
    const int E = in_sizes[1] / 2;       // 3200000
    const int nb = (N + 255) >> BSH;     // 391 buckets

    // workspace layout
    __hip_bfloat16* h = (__hip_bfloat16*)d_ws;     // N*HID bf16 (12.8 MB)
    float* a_src_d = (float*)(h + (size_t)N * HID);// N
    float* a_dst_d = a_src_d + N;                  // N
    float2* adi    = (float2*)(a_dst_d + N);       // N float2 (a_dst, inv_s)
    int* row_start = (int*)(adi + N);              // N
    int* cnt       = row_start + N;                // N
    int* g_cursor  = cnt + N;                      // 512
    int* pairs     = g_cursor + 512;               // nb*CAP
    int* csr_src   = pairs + (size_t)nb * CAP;     // E

    float* out       = (float*)d_out;              // N*HID
    float* out_alpha = out + (size_t)N * HID;      // E+N

    k_gemm<<<(N + 127) / 128, 256, 0, stream>>>(x, W, att_src, att_dst,
                                                (short*)h, a_src_d, a_dst_d,
                                                g_cursor, N);

    void* sargs[] = { (void*)&ei, (void*)&g_cursor, (void*)&pairs,
                      (void*)&row_start, (void*)&cnt, (void*)&csr_src,
                      (void*)&E, (void*)&N, (void*)&nb };
    hipLaunchCooperativeKernel((void*)k_sort, dim3(nb), dim3(512),
                               sargs, 0, stream);

    k_agg<<<(N + 7) / 8, 256, 0, stream>>>(h, a_src_d, a_dst_d, bias,
                                           row_start, cnt, csr_src,
                                           out, adi, N);
    k_alpha<<<((E >> 2) + N + 255) / 256, 256, 0, stream>>>(ei, a_src_d, adi,
                                                            out_alpha, E, N);
}

// Round 7
// 284.680 us; speedup vs baseline: 1.1977x; 1.1977x over previous
//
#include <hip/hip_runtime.h>
#include <hip/hip_bf16.h>

#define IN_CH 128
#define HID 64
#define NEG_SLOPE 0.2f
#define BSH 8            // bucket = dst >> 8  (256 dsts per bucket)
#define CAP 10240        // per-bucket capacity (mean 8184, ~20-sigma slack)

typedef __attribute__((ext_vector_type(8))) short short8;   // bf16x8 frag (4 VGPRs)
typedef __attribute__((ext_vector_type(4))) float floatx4;  // fp32x4 acc
typedef __attribute__((ext_vector_type(2))) float f32x2;    // packed fma pair

__device__ inline short bfr(float f) {   // fp32 -> bf16 bits, round-nearest-even
    unsigned u = __float_as_uint(f);
    u += 0x7fffu + ((u >> 16) & 1u);
    return (short)(u >> 16);
}

// ---------------------------------------------------------------------------
// h = x @ W via mfma_f32_16x16x32_bf16, with W-fragment prep fused (pad-65
// LDS staging, 2-way reads = free). Block 0 zeroes g_cursor.
// C-layout: col = lane&15, row = quad*4 + reg  [m89].
// ---------------------------------------------------------------------------
__global__ __launch_bounds__(256) void k_gemm(
    const float* __restrict__ x, const float* __restrict__ W,
    const float* __restrict__ att_src, const float* __restrict__ att_dst,
    short* __restrict__ h, float* __restrict__ a_src,
    float* __restrict__ a_dst, int* __restrict__ g_cursor, int N)
{
    __shared__ float wlds[IN_CH * 65];   // pad 65: conflict-free column reads

    const int t = threadIdx.x;
    const int lane = t & 63;
    const int wv = t >> 6;
    const int l15 = lane & 15;
    const int quad = lane >> 4;

    if (blockIdx.x == 0) { g_cursor[t] = 0; g_cursor[t + 256] = 0; }

    // stage W: 2048 float4 loads, write into padded rows (4-float runs)
#pragma unroll
    for (int r = 0; r < 8; ++r) {
        const int idx4 = r * 256 + t;
        const float4 w4 = ((const float4*)W)[idx4];
        const int fi = idx4 * 4;
        float* dst = &wlds[(fi >> 6) * 65 + (fi & 63)];
        dst[0] = w4.x; dst[1] = w4.y; dst[2] = w4.z; dst[3] = w4.w;
    }
    __syncthreads();

    // build B fragments: frag f = kt*4+nt; lane holds B[k0+j][n]
    short8 bf[16];
#pragma unroll
    for (int f = 0; f < 16; ++f) {
        const int kt = f >> 2, nt = f & 3;
        const int k0 = kt * 32 + quad * 8;
        const int n = nt * 16 + l15;
        short8 a;
#pragma unroll
        for (int j = 0; j < 8; ++j) a[j] = bfr(wlds[(k0 + j) * 65 + n]);
        bf[f] = a;
    }

    float as4[4], ad4[4];
#pragma unroll
    for (int nt = 0; nt < 4; ++nt) {
        as4[nt] = att_src[nt * 16 + l15];
        ad4[nt] = att_dst[nt * 16 + l15];
    }

    const int rowbase = blockIdx.x * 128 + wv * 32;

#pragma unroll
    for (int mt = 0; mt < 2; ++mt) {
        const int m0 = rowbase + mt * 16;
        const int rowa = m0 + l15;
        const int rowc = rowa < N ? rowa : N - 1;   // clamp loads
        const float* xp = x + (size_t)rowc * IN_CH + quad * 8;

        short8 af[4];
#pragma unroll
        for (int kt = 0; kt < 4; ++kt) {
            float4 p0 = *(const float4*)(xp + kt * 32);
            float4 p1 = *(const float4*)(xp + kt * 32 + 4);
            short8 a;
            a[0] = bfr(p0.x); a[1] = bfr(p0.y); a[2] = bfr(p0.z); a[3] = bfr(p0.w);
            a[4] = bfr(p1.x); a[5] = bfr(p1.y); a[6] = bfr(p1.z); a[7] = bfr(p1.w);
            af[kt] = a;
        }

        floatx4 acc[4];
#pragma unroll
        for (int nt = 0; nt < 4; ++nt) acc[nt] = (floatx4){0.f, 0.f, 0.f, 0.f};
#pragma unroll
        for (int kt = 0; kt < 4; ++kt)
#pragma unroll
            for (int nt = 0; nt < 4; ++nt)
                acc[nt] = __builtin_amdgcn_mfma_f32_16x16x32_bf16(
                    af[kt], bf[kt * 4 + nt], acc[nt], 0, 0, 0);

        // epilogue: rows m0 + quad*4 + r
#pragma unroll
        for (int r = 0; r < 4; ++r) {
            const int row = m0 + quad * 4 + r;
            const bool ok = row < N;
            if (ok) {
#pragma unroll
                for (int nt = 0; nt < 4; ++nt)
                    h[(size_t)row * HID + nt * 16 + l15] = bfr(acc[nt][r]);
            }
            float ps = acc[0][r] * as4[0] + acc[1][r] * as4[1] +
                       acc[2][r] * as4[2] + acc[3][r] * as4[3];
            float pd = acc[0][r] * ad4[0] + acc[1][r] * ad4[1] +
                       acc[2][r] * ad4[2] + acc[3][r] * ad4[3];
#pragma unroll
            for (int m2 = 1; m2 < 16; m2 <<= 1) {
                ps += __shfl_xor(ps, m2, 64);
                pd += __shfl_xor(pd, m2, 64);
            }
            if (ok && l15 == 0) { a_src[row] = ps; a_dst[row] = pd; }
        }
    }
}

// ---------------------------------------------------------------------------
// Bucket pass (782 blocks x 256 thr): bin edges by dst>>8, rank captured in
// the counting pass. Packed payload: s | (dst&255)<<17.
// ---------------------------------------------------------------------------
__global__ __launch_bounds__(256) void k_binB(
    const int* __restrict__ ei, int* __restrict__ g_cursor,
    int* __restrict__ pairs, int E, int nb)
{
    __shared__ int hist[512];
    __shared__ int base[512];
    const int t = threadIdx.x;
    hist[t] = 0;
    hist[t + 256] = 0;
    __syncthreads();

    int s[16], d[16], l[16];
    const int4* s4 = (const int4*)ei;
    const int4* d4 = (const int4*)(ei + E);
    const int E4 = E >> 2;
    const int q0 = blockIdx.x * 1024;
#pragma unroll
    for (int i = 0; i < 4; ++i) {
        int q = q0 + i * 256 + t;
        int4 sv = make_int4(0, 0, 0, 0);
        int4 dv = make_int4(-1, -1, -1, -1);
        if (q < E4) { sv = s4[q]; dv = d4[q]; }
        s[4 * i + 0] = sv.x; s[4 * i + 1] = sv.y; s[4 * i + 2] = sv.z; s[4 * i + 3] = sv.w;
        d[4 * i + 0] = dv.x; d[4 * i + 1] = dv.y; d[4 * i + 2] = dv.z; d[4 * i + 3] = dv.w;
    }
#pragma unroll
    for (int i = 0; i < 16; ++i)
        if (d[i] >= 0) l[i] = atomicAdd(&hist[d[i] >> BSH], 1);
    __syncthreads();

    if (t < nb) base[t] = atomicAdd(&g_cursor[t], hist[t]);
    if (t + 256 < nb) base[t + 256] = atomicAdd(&g_cursor[t + 256], hist[t + 256]);
    __syncthreads();

#pragma unroll
    for (int i = 0; i < 16; ++i) {
        if (d[i] < 0) continue;
        int b = d[i] >> BSH;
        int pos = base[b] + l[i];
        if (pos < CAP)
            pairs[b * CAP + pos] = s[i] | ((d[i] & 255) << 17);
    }
}

// ---------------------------------------------------------------------------
// Per-bucket finalize (round-4 two-pass form, low VGPR): one block (512 thr)
// per 256-dst bucket. In-block redundant scan of bucket counts -> base; LDS
// per-dst hist -> scan -> row_start/cnt -> scatter csr into L2-local window.
// ---------------------------------------------------------------------------
__global__ __launch_bounds__(512) void k_binC(
    const int* __restrict__ pairs, const int* __restrict__ g_cursor,
    int* __restrict__ row_start, int* __restrict__ cnt,
    int* __restrict__ csr_src, int N, int nb)
{
    __shared__ int h0[256];
    __shared__ int hs[512];
    __shared__ int cur[256];
    __shared__ int sbase;
    const int t = threadIdx.x;
    const int b = blockIdx.x;
    int m = g_cursor[b];
    if (m > CAP) m = CAP;
    const int* pb = pairs + b * CAP;

    // exclusive bucket-base via redundant in-block scan over nb (<512) entries
    int bv = (t < nb) ? g_cursor[t] : 0;
    hs[t] = bv;
    __syncthreads();
    for (int off = 1; off < 512; off <<= 1) {
        int u = (t >= off) ? hs[t - off] : 0;
        __syncthreads();
        hs[t] += u;
        __syncthreads();
    }
    if (t == b) sbase = hs[t] - bv;
    if (t < 256) h0[t] = 0;
    __syncthreads();
    const int basec = sbase;

    for (int i = t; i < m; i += 512)
        atomicAdd(&h0[pb[i] >> 17], 1);
    __syncthreads();

    // scan the 256 per-dst counts (guarded; barriers stay uniform)
    if (t < 256) hs[t] = h0[t];
    __syncthreads();
    for (int off = 1; off < 256; off <<= 1) {
        int u = (t >= off && t < 256) ? hs[t - off] : 0;
        __syncthreads();
        if (t < 256) hs[t] += u;
        __syncthreads();
    }
    if (t < 256) {
        const int excl = hs[t] - h0[t];
        cur[t] = basec + excl;
        const int dd = (b << BSH) + t;
        if (dd < N) { row_start[dd] = basec + excl; cnt[dd] = h0[t]; }
    }
    __syncthreads();

    for (int i = t; i < m; i += 512) {
        int p = pb[i];
        int pos = atomicAdd(&cur[p >> 17], 1);
        csr_src[pos] = p & 0x1FFFF;
    }
}

// ---------------------------------------------------------------------------
// Aggregation: two dsts per wave, interleaved (proven 63 us form, inner loop
// byte-identical). dbase allows launching as two half-range dispatches so
// other kernels can surface in the rocprof top-5 (visibility split).
// ---------------------------------------------------------------------------
__global__ __launch_bounds__(256) void k_agg(
    const __hip_bfloat16* __restrict__ h, const float* __restrict__ a_src,
    const float* __restrict__ a_dst, const float* __restrict__ bias,
    const int* __restrict__ row_start, const int* __restrict__ cnt,
    const int* __restrict__ csr_src,
    float* __restrict__ out, float2* __restrict__ adi, int dbase, int N)
{
    __shared__ float red[4][2][576];   // [wave][dst][ch*9+q], pad 9

    const int wave = threadIdx.x >> 6;
    const int lane = threadIdx.x & 63;
    const int d0 = dbase + blockIdx.x * 8 + wave * 2;
    if (d0 >= N) return;
    const int d1 = d0 + 1;
    const bool has1 = d1 < N;

    const int q  = lane >> 3;   // row slot within group of 8
    const int i8 = lane & 7;    // 16-B chunk of the 128-B row

    const float2 ad2 = *(const float2*)(a_dst + d0);   // d0 even
    const float ad0 = ad2.x;
    const float ad1 = ad2.y;
    const int2 cn2 = *(const int2*)(cnt + d0);
    const int n0 = cn2.x;
    const int n1 = has1 ? cn2.y : 0;
    const int st0 = row_start[d0];
    const int en0 = st0 + n0;
    const int st1 = en0;                 // CSR globally contiguous
    const int en1 = st1 + n1;

    const uint4* h4 = (const uint4*)h;

    float ps0 = 0.f, ps1 = 0.f;
    f32x2 ac0[4], ac1[4];
#pragma unroll
    for (int c = 0; c < 4; ++c) {
        ac0[c] = (f32x2){0.f, 0.f};
        ac1[c] = (f32x2){0.f, 0.f};
    }

    const int nbt0 = (n0 + 63) >> 6;
    const int nbt1 = (n1 + 63) >> 6;
    const int nbm = nbt0 > nbt1 ? nbt0 : nbt1;

    int b0 = st0, b1 = st1;
    for (int it = 0; it < nbm; ++it, b0 += 64, b1 += 64) {
        int s0v = 0, s1v = 0;
        float e0 = 0.f, e1 = 0.f;
        const int idx0 = b0 + lane;
        if (it < nbt0 && idx0 < en0) {
            s0v = csr_src[idx0];
            float v = a_src[s0v] + ad0;
            v = v > 0.f ? v : NEG_SLOPE * v;
            e0 = __expf(v);
            ps0 += e0;
        }
        const int idx1 = b1 + lane;
        if (it < nbt1 && idx1 < en1) {
            s1v = csr_src[idx1];
            float v = a_src[s1v] + ad1;
            v = v > 0.f ? v : NEG_SLOPE * v;
            e1 = __expf(v);
            ps1 += e1;
        }
        const int m0 = (it < nbt0) ? min(64, en0 - b0) : 0;
        const int m1 = (it < nbt1) ? min(64, en1 - b1) : 0;
        const int mm = m0 > m1 ? m0 : m1;
#pragma unroll 4
        for (int j = 0; j < mm; j += 8) {
            const int jq = j + q;
            const int sj0 = __shfl(s0v, jq, 64);    // inactive slots: s=0,e=0
            const float ej0 = __shfl(e0, jq, 64);   // -> harmless row-0 load
            const int sj1 = __shfl(s1v, jq, 64);
            const float ej1 = __shfl(e1, jq, 64);
            uint4 u0 = h4[(size_t)sj0 * 8 + i8];
            uint4 u1 = h4[(size_t)sj1 * 8 + i8];
            f32x2 ev0; ev0[0] = ej0; ev0[1] = ej0;
            f32x2 ev1; ev1[0] = ej1; ev1[1] = ej1;
            f32x2 c;
            c[0] = __uint_as_float(u0.x << 16);
            c[1] = __uint_as_float(u0.x & 0xffff0000u);
            ac0[0] = __builtin_elementwise_fma(ev0, c, ac0[0]);
            c[0] = __uint_as_float(u0.y << 16);
            c[1] = __uint_as_float(u0.y & 0xffff0000u);
            ac0[1] = __builtin_elementwise_fma(ev0, c, ac0[1]);
            c[0] = __uint_as_float(u0.z << 16);
            c[1] = __uint_as_float(u0.z & 0xffff0000u);
            ac0[2] = __builtin_elementwise_fma(ev0, c, ac0[2]);
            c[0] = __uint_as_float(u0.w << 16);
            c[1] = __uint_as_float(u0.w & 0xffff0000u);
            ac0[3] = __builtin_elementwise_fma(ev0, c, ac0[3]);
            c[0] = __uint_as_float(u1.x << 16);
            c[1] = __uint_as_float(u1.x & 0xffff0000u);
            ac1[0] = __builtin_elementwise_fma(ev1, c, ac1[0]);
            c[0] = __uint_as_float(u1.y << 16);
            c[1] = __uint_as_float(u1.y & 0xffff0000u);
            ac1[1] = __builtin_elementwise_fma(ev1, c, ac1[1]);
            c[0] = __uint_as_float(u1.z << 16);
            c[1] = __uint_as_float(u1.z & 0xffff0000u);
            ac1[2] = __builtin_elementwise_fma(ev1, c, ac1[2]);
            c[0] = __uint_as_float(u1.w << 16);
            c[1] = __uint_as_float(u1.w & 0xffff0000u);
            ac1[3] = __builtin_elementwise_fma(ev1, c, ac1[3]);
        }
    }

    // stash partials to LDS, channel-major pad-9: addr = ch*9 + q with
    // ch = i8*8 + c. Write banks = bit-swap(lane) perm -> 2-way (free).
    float* r0 = &red[wave][0][0];
    float* r1 = &red[wave][1][0];
#pragma unroll
    for (int p = 0; p < 4; ++p) {
        r0[(i8 * 8 + 2 * p) * 9 + q]     = ac0[p][0];
        r0[(i8 * 8 + 2 * p + 1) * 9 + q] = ac0[p][1];
        r1[(i8 * 8 + 2 * p) * 9 + q]     = ac1[p][0];
        r1[(i8 * 8 + 2 * p + 1) * 9 + q] = ac1[p][1];
    }

    // psum reduce (overlaps LDS settle)
#pragma unroll
    for (int m2 = 32; m2 > 0; m2 >>= 1) {
        ps0 += __shfl_xor(ps0, m2, 64);
        ps1 += __shfl_xor(ps1, m2, 64);
    }

    const float2 asd = *(const float2*)(a_src + d0);
    float vs0 = asd.x + ad0;
    vs0 = vs0 > 0.f ? vs0 : NEG_SLOPE * vs0;
    const float es0 = __expf(vs0);
    const float inv0 = 1.f / (ps0 + es0);
    float es1 = 0.f, inv1 = 0.f;
    if (has1) {
        float vs1 = asd.y + ad1;
        vs1 = vs1 > 0.f ? vs1 : NEG_SLOPE * vs1;
        es1 = __expf(vs1);
        inv1 = 1.f / (ps1 + es1);
    }
    if (lane == 0) {
        adi[d0] = make_float2(ad0, inv0);
        if (has1) adi[d1] = make_float2(ad1, inv1);
    }

    // lane t owns channel ch == lane: sum its 8 q-partials
    float s0 = 0.f, s1 = 0.f;
#pragma unroll
    for (int qq = 0; qq < 8; ++qq) {
        s0 += r0[lane * 9 + qq];
        s1 += r1[lane * 9 + qq];
    }

    const ushort* hu = (const ushort*)h;
    const float bi = bias[lane];
    float hs0 = __uint_as_float(((unsigned)hu[(size_t)d0 * HID + lane]) << 16);
    out[(size_t)d0 * HID + lane] = fmaf(es0, hs0, s0) * inv0 + bi;
    if (has1) {
        float hs1 = __uint_as_float(((unsigned)hu[(size_t)d1 * HID + lane]) << 16);
        out[(size_t)d1 * HID + lane] = fmaf(es1, hs1, s1) * inv1 + bi;
    }
}

// ---------------------------------------------------------------------------
// edge-order alpha, vectorized 4-wide: int4 index loads, float4 stores.
// Self-loop entries (alpha[E..E+N)) handled as the tail thread range.
// ---------------------------------------------------------------------------
__global__ void k_alpha(const int* __restrict__ ei,
                        const float* __restrict__ a_src,
                        const float2* __restrict__ adi,
                        float* __restrict__ out_alpha, int E, int N)
{
    const int E4 = E >> 2;
    const int i = blockIdx.x * 256 + threadIdx.x;
    if (i < E4) {
        const int4 sv = ((const int4*)ei)[i];
        const int4 dv = ((const int4*)(ei + E))[i];
        float4 o;
        {
            const float2 av = adi[dv.x];
            float v = a_src[sv.x] + av.x;
            v = v > 0.f ? v : NEG_SLOPE * v;
            o.x = __expf(v) * av.y;
        }
        {
            const float2 av = adi[dv.y];
            float v = a_src[sv.y] + av.x;
            v = v > 0.f ? v : NEG_SLOPE * v;
            o.y = __expf(v) * av.y;
        }
        {
            const float2 av = adi[dv.z];
            float v = a_src[sv.z] + av.x;
            v = v > 0.f ? v : NEG_SLOPE * v;
            o.z = __expf(v) * av.y;
        }
        {
            const float2 av = adi[dv.w];
            float v = a_src[sv.w] + av.x;
            v = v > 0.f ? v : NEG_SLOPE * v;
            o.w = __expf(v) * av.y;
        }
        ((float4*)out_alpha)[i] = o;
    } else {
        const int j = i - E4;
        if (j < N) {
            const float2 av = adi[j];
            float v = a_src[j] + av.x;
            v = v > 0.f ? v : NEG_SLOPE * v;
            out_alpha[E + j] = __expf(v) * av.y;
        }
    }
}

// ---------------------------------------------------------------------------
extern "C" void kernel_launch(void* const* d_in, const int* in_sizes, int n_in,
                              void* d_out, int out_size, void* d_ws, size_t ws_size,
                              hipStream_t stream)
{
    (void)n_in; (void)out_size; (void)ws_size;
    const float* x       = (const float*)d_in[0];
    const int*   ei      = (const int*)d_in[1];
    const float* W       = (const float*)d_in[2];
    const float* att_src = (const float*)d_in[3];
    const float* att_dst = (const float*)d_in[4];
    const float* bias    = (const float*)d_in[5];

    const int N = in_sizes[0] / IN_CH;   // 100000
    const int E = in_sizes[1] / 2;       // 3200000
    const int nb = (N + 255) >> BSH;     // 391 buckets

    // workspace layout
    __hip_bfloat16* h = (__hip_bfloat16*)d_ws;     // N*HID bf16 (12.8 MB)
    float* a_src_d = (float*)(h + (size_t)N * HID);// N
    float* a_dst_d = a_src_d + N;                  // N
    float2* adi    = (float2*)(a_dst_d + N);       // N float2 (a_dst, inv_s)
    int* row_start = (int*)(adi + N);              // N
    int* cnt       = row_start + N;                // N
    int* g_cursor  = cnt + N;                      // 512
    int* pairs     = g_cursor + 512;               // nb*CAP
    int* csr_src   = pairs + (size_t)nb * CAP;     // E

    float* out       = (float*)d_out;              // N*HID
    float* out_alpha = out + (size_t)N * HID;      // E+N

    k_gemm<<<(N + 127) / 128, 256, 0, stream>>>(x, W, att_src, att_dst,
                                                (short*)h, a_src_d, a_dst_d,
                                                g_cursor, N);
    k_binB<<<(E / 4 + 1023) / 1024, 256, 0, stream>>>(ei, g_cursor, pairs, E, nb);
    k_binC<<<nb, 512, 0, stream>>>(pairs, g_cursor,
                                   row_start, cnt, csr_src, N, nb);

    // k_agg split into two half-range dispatches (~32 us each): same total
    // work, same occupancy; lets kernels >~33 us surface in rocprof top-5.
    const int H = 50000;                 // multiple of 8, = N/2
    k_agg<<<(H + 7) / 8, 256, 0, stream>>>(h, a_src_d, a_dst_d, bias,
                                           row_start, cnt, csr_src,
                                           out, adi, 0, H);
    k_agg<<<(N - H + 7) / 8, 256, 0, stream>>>(h, a_src_d, a_dst_d, bias,
                                               row_start, cnt, csr_src,
                                               out, adi, H, N);
    k_alpha<<<((E >> 2) + N + 255) / 256, 256, 0, stream>>>(ei, a_src_d, adi,
                                                            out_alpha, E, N);
}

// Round 8
// 275.882 us; speedup vs baseline: 1.2359x; 1.0319x over previous
//
#include <hip/hip_runtime.h>
#include <hip/hip_bf16.h>

#define IN_CH 128
#define HID 64
#define NEG_SLOPE 0.2f
#define BSH 8            // bucket = dst >> 8  (256 dsts per bucket)
#define CAP 10240        // per-bucket capacity (mean 8184, ~20-sigma slack)

typedef __attribute__((ext_vector_type(8))) short short8;   // bf16x8 frag (4 VGPRs)
typedef __attribute__((ext_vector_type(4))) float floatx4;  // fp32x4 acc
typedef __attribute__((ext_vector_type(2))) float f32x2;    // packed fma pair

__device__ inline short bfr(float f) {   // fp32 -> bf16 bits, round-nearest-even
    unsigned u = __float_as_uint(f);
    u += 0x7fffu + ((u >> 16) & 1u);
    return (short)(u >> 16);
}

// ---------------------------------------------------------------------------
// One-time: repack W (128x64 fp32) into bf16 MFMA B-fragments; block 0 also
// zeroes g_cursor (512 entries). (Separate prep proved faster than fusing
// the staging into every gemm block — round 6/7 regression.)
// ---------------------------------------------------------------------------
__global__ void k_prep(const float* __restrict__ W, short* __restrict__ wfrag,
                       int* __restrict__ g_cursor)
{
    if (blockIdx.x == 0) {
        g_cursor[threadIdx.x] = 0;
        g_cursor[threadIdx.x + 256] = 0;
    }
    int idx = blockIdx.x * 256 + threadIdx.x;
    if (idx >= 1024) return;
    int f = idx >> 6, l = idx & 63;
    int kt = f >> 2, nt = f & 3;
    int k0 = kt * 32 + (l >> 4) * 8;
    int n = nt * 16 + (l & 15);
#pragma unroll
    for (int j = 0; j < 8; ++j)
        wfrag[idx * 8 + j] = bfr(W[(k0 + j) * HID + n]);
}

// ---------------------------------------------------------------------------
// h = x @ W via mfma_f32_16x16x32_bf16. Block 256 = 4 waves; each wave does
// 2 M-tiles of 16 rows; B-fragments loaded coalesced from wfrag.
// C-layout: col = lane&15, row = quad*4 + reg  [m89].
// ---------------------------------------------------------------------------
__global__ __launch_bounds__(256) void k_gemm(
    const float* __restrict__ x, const short8* __restrict__ wfrag,
    const float* __restrict__ att_src, const float* __restrict__ att_dst,
    short* __restrict__ h, float* __restrict__ a_src,
    float* __restrict__ a_dst, int N)
{
    const int t = threadIdx.x;
    const int lane = t & 63;
    const int wv = t >> 6;
    const int l15 = lane & 15;
    const int quad = lane >> 4;

    short8 bf[16];
#pragma unroll
    for (int f = 0; f < 16; ++f) bf[f] = wfrag[f * 64 + lane];

    float as4[4], ad4[4];
#pragma unroll
    for (int nt = 0; nt < 4; ++nt) {
        as4[nt] = att_src[nt * 16 + l15];
        ad4[nt] = att_dst[nt * 16 + l15];
    }

    const int rowbase = blockIdx.x * 128 + wv * 32;

#pragma unroll
    for (int mt = 0; mt < 2; ++mt) {
        const int m0 = rowbase + mt * 16;
        const int rowa = m0 + l15;
        const int rowc = rowa < N ? rowa : N - 1;   // clamp loads
        const float* xp = x + (size_t)rowc * IN_CH + quad * 8;

        short8 af[4];
#pragma unroll
        for (int kt = 0; kt < 4; ++kt) {
            float4 p0 = *(const float4*)(xp + kt * 32);
            float4 p1 = *(const float4*)(xp + kt * 32 + 4);
            short8 a;
            a[0] = bfr(p0.x); a[1] = bfr(p0.y); a[2] = bfr(p0.z); a[3] = bfr(p0.w);
            a[4] = bfr(p1.x); a[5] = bfr(p1.y); a[6] = bfr(p1.z); a[7] = bfr(p1.w);
            af[kt] = a;
        }

        floatx4 acc[4];
#pragma unroll
        for (int nt = 0; nt < 4; ++nt) acc[nt] = (floatx4){0.f, 0.f, 0.f, 0.f};
#pragma unroll
        for (int kt = 0; kt < 4; ++kt)
#pragma unroll
            for (int nt = 0; nt < 4; ++nt)
                acc[nt] = __builtin_amdgcn_mfma_f32_16x16x32_bf16(
                    af[kt], bf[kt * 4 + nt], acc[nt], 0, 0, 0);

        // epilogue: rows m0 + quad*4 + r
#pragma unroll
        for (int r = 0; r < 4; ++r) {
            const int row = m0 + quad * 4 + r;
            const bool ok = row < N;
            if (ok) {
#pragma unroll
                for (int nt = 0; nt < 4; ++nt)
                    h[(size_t)row * HID + nt * 16 + l15] = bfr(acc[nt][r]);
            }
            float ps = acc[0][r] * as4[0] + acc[1][r] * as4[1] +
                       acc[2][r] * as4[2] + acc[3][r] * as4[3];
            float pd = acc[0][r] * ad4[0] + acc[1][r] * ad4[1] +
                       acc[2][r] * ad4[2] + acc[3][r] * ad4[3];
#pragma unroll
            for (int m2 = 1; m2 < 16; m2 <<= 1) {
                ps += __shfl_xor(ps, m2, 64);
                pd += __shfl_xor(pd, m2, 64);
            }
            if (ok && l15 == 0) { a_src[row] = ps; a_dst[row] = pd; }
        }
    }
}

// ---------------------------------------------------------------------------
// Bucket pass, wave-rich form: 512 threads (8 waves/block, ~24 waves/CU vs
// 12 before -> 2x memory-level parallelism for the latency-bound scatter),
// 8 edges/thread, same 782-block grid. Rank captured in the counting pass.
// Packed payload: s | (dst&255)<<17.
// ---------------------------------------------------------------------------
__global__ __launch_bounds__(512) void k_binB(
    const int* __restrict__ ei, int* __restrict__ g_cursor,
    int* __restrict__ pairs, int E, int nb)
{
    __shared__ int hist[512];
    __shared__ int base[512];
    const int t = threadIdx.x;
    hist[t] = 0;
    __syncthreads();

    int s[8], d[8], l[8];
    const int4* s4 = (const int4*)ei;
    const int4* d4 = (const int4*)(ei + E);
    const int E4 = E >> 2;
    const int q0 = blockIdx.x * 1024;
#pragma unroll
    for (int i = 0; i < 2; ++i) {
        int q = q0 + i * 512 + t;
        int4 sv = make_int4(0, 0, 0, 0);
        int4 dv = make_int4(-1, -1, -1, -1);
        if (q < E4) { sv = s4[q]; dv = d4[q]; }
        s[4 * i + 0] = sv.x; s[4 * i + 1] = sv.y; s[4 * i + 2] = sv.z; s[4 * i + 3] = sv.w;
        d[4 * i + 0] = dv.x; d[4 * i + 1] = dv.y; d[4 * i + 2] = dv.z; d[4 * i + 3] = dv.w;
    }
#pragma unroll
    for (int i = 0; i < 8; ++i)
        if (d[i] >= 0) l[i] = atomicAdd(&hist[d[i] >> BSH], 1);
    __syncthreads();

    if (t < nb) base[t] = atomicAdd(&g_cursor[t], hist[t]);
    __syncthreads();

#pragma unroll
    for (int i = 0; i < 8; ++i) {
        if (d[i] < 0) continue;
        int b = d[i] >> BSH;
        int pos = base[b] + l[i];
        if (pos < CAP)
            pairs[b * CAP + pos] = s[i] | ((d[i] & 255) << 17);
    }
}

// ---------------------------------------------------------------------------
// Per-bucket finalize: one block (512 thr) per 256-dst bucket. Two-pass over
// the bucket window with INT4 reads (1/4 the load issues). In-block redundant
// scan of bucket counts -> base; LDS per-dst hist -> scan -> row_start/cnt ->
// scatter csr into the bucket's L2-local window.
// ---------------------------------------------------------------------------
__global__ __launch_bounds__(512) void k_binC(
    const int* __restrict__ pairs, const int* __restrict__ g_cursor,
    int* __restrict__ row_start, int* __restrict__ cnt,
    int* __restrict__ csr_src, int N, int nb)
{
    __shared__ int h0[256];
    __shared__ int hs[512];
    __shared__ int cur[256];
    __shared__ int sbase;
    const int t = threadIdx.x;
    const int b = blockIdx.x;
    int m = g_cursor[b];
    if (m > CAP) m = CAP;
    const int4* pb4 = (const int4*)(pairs + b * CAP);
    const int m4 = (m + 3) >> 2;

    // exclusive bucket-base via redundant in-block scan over nb (<512) entries
    int bv = (t < nb) ? g_cursor[t] : 0;
    hs[t] = bv;
    __syncthreads();
    for (int off = 1; off < 512; off <<= 1) {
        int u = (t >= off) ? hs[t - off] : 0;
        __syncthreads();
        hs[t] += u;
        __syncthreads();
    }
    if (t == b) sbase = hs[t] - bv;
    if (t < 256) h0[t] = 0;
    __syncthreads();
    const int basec = sbase;

    for (int i4 = t; i4 < m4; i4 += 512) {
        const int4 p = pb4[i4];
        const int i = i4 << 2;
        if (i + 3 < m) {
            atomicAdd(&h0[p.x >> 17], 1);
            atomicAdd(&h0[p.y >> 17], 1);
            atomicAdd(&h0[p.z >> 17], 1);
            atomicAdd(&h0[p.w >> 17], 1);
        } else {
            if (i     < m) atomicAdd(&h0[p.x >> 17], 1);
            if (i + 1 < m) atomicAdd(&h0[p.y >> 17], 1);
            if (i + 2 < m) atomicAdd(&h0[p.z >> 17], 1);
        }
    }
    __syncthreads();

    // scan the 256 per-dst counts (guarded; barriers stay uniform)
    if (t < 256) hs[t] = h0[t];
    __syncthreads();
    for (int off = 1; off < 256; off <<= 1) {
        int u = (t >= off && t < 256) ? hs[t - off] : 0;
        __syncthreads();
        if (t < 256) hs[t] += u;
        __syncthreads();
    }
    if (t < 256) {
        const int excl = hs[t] - h0[t];
        cur[t] = basec + excl;
        const int dd = (b << BSH) + t;
        if (dd < N) { row_start[dd] = basec + excl; cnt[dd] = h0[t]; }
    }
    __syncthreads();

    for (int i4 = t; i4 < m4; i4 += 512) {
        const int4 p = pb4[i4];
        const int i = i4 << 2;
        if (i < m) {
            int pos = atomicAdd(&cur[p.x >> 17], 1);
            csr_src[pos] = p.x & 0x1FFFF;
        }
        if (i + 1 < m) {
            int pos = atomicAdd(&cur[p.y >> 17], 1);
            csr_src[pos] = p.y & 0x1FFFF;
        }
        if (i + 2 < m) {
            int pos = atomicAdd(&cur[p.z >> 17], 1);
            csr_src[pos] = p.z & 0x1FFFF;
        }
        if (i + 3 < m) {
            int pos = atomicAdd(&cur[p.w >> 17], 1);
            csr_src[pos] = p.w & 0x1FFFF;
        }
    }
}

// ---------------------------------------------------------------------------
// Aggregation: two dsts per wave, interleaved (proven 63 us form, inner loop
// byte-identical). dbase allows the two half-range dispatches (visibility).
// ---------------------------------------------------------------------------
__global__ __launch_bounds__(256) void k_agg(
    const __hip_bfloat16* __restrict__ h, const float* __restrict__ a_src,
    const float* __restrict__ a_dst, const float* __restrict__ bias,
    const int* __restrict__ row_start, const int* __restrict__ cnt,
    const int* __restrict__ csr_src,
    float* __restrict__ out, float2* __restrict__ adi, int dbase, int N)
{
    __shared__ float red[4][2][576];   // [wave][dst][ch*9+q], pad 9

    const int wave = threadIdx.x >> 6;
    const int lane = threadIdx.x & 63;
    const int d0 = dbase + blockIdx.x * 8 + wave * 2;
    if (d0 >= N) return;
    const int d1 = d0 + 1;
    const bool has1 = d1 < N;

    const int q  = lane >> 3;   // row slot within group of 8
    const int i8 = lane & 7;    // 16-B chunk of the 128-B row

    const float2 ad2 = *(const float2*)(a_dst + d0);   // d0 even
    const float ad0 = ad2.x;
    const float ad1 = ad2.y;
    const int2 cn2 = *(const int2*)(cnt + d0);
    const int n0 = cn2.x;
    const int n1 = has1 ? cn2.y : 0;
    const int st0 = row_start[d0];
    const int en0 = st0 + n0;
    const int st1 = en0;                 // CSR globally contiguous
    const int en1 = st1 + n1;

    const uint4* h4 = (const uint4*)h;

    float ps0 = 0.f, ps1 = 0.f;
    f32x2 ac0[4], ac1[4];
#pragma unroll
    for (int c = 0; c < 4; ++c) {
        ac0[c] = (f32x2){0.f, 0.f};
        ac1[c] = (f32x2){0.f, 0.f};
    }

    const int nbt0 = (n0 + 63) >> 6;
    const int nbt1 = (n1 + 63) >> 6;
    const int nbm = nbt0 > nbt1 ? nbt0 : nbt1;

    int b0 = st0, b1 = st1;
    for (int it = 0; it < nbm; ++it, b0 += 64, b1 += 64) {
        int s0v = 0, s1v = 0;
        float e0 = 0.f, e1 = 0.f;
        const int idx0 = b0 + lane;
        if (it < nbt0 && idx0 < en0) {
            s0v = csr_src[idx0];
            float v = a_src[s0v] + ad0;
            v = v > 0.f ? v : NEG_SLOPE * v;
            e0 = __expf(v);
            ps0 += e0;
        }
        const int idx1 = b1 + lane;
        if (it < nbt1 && idx1 < en1) {
            s1v = csr_src[idx1];
            float v = a_src[s1v] + ad1;
            v = v > 0.f ? v : NEG_SLOPE * v;
            e1 = __expf(v);
            ps1 += e1;
        }
        const int m0 = (it < nbt0) ? min(64, en0 - b0) : 0;
        const int m1 = (it < nbt1) ? min(64, en1 - b1) : 0;
        const int mm = m0 > m1 ? m0 : m1;
#pragma unroll 4
        for (int j = 0; j < mm; j += 8) {
            const int jq = j + q;
            const int sj0 = __shfl(s0v, jq, 64);    // inactive slots: s=0,e=0
            const float ej0 = __shfl(e0, jq, 64);   // -> harmless row-0 load
            const int sj1 = __shfl(s1v, jq, 64);
            const float ej1 = __shfl(e1, jq, 64);
            uint4 u0 = h4[(size_t)sj0 * 8 + i8];
            uint4 u1 = h4[(size_t)sj1 * 8 + i8];
            f32x2 ev0; ev0[0] = ej0; ev0[1] = ej0;
            f32x2 ev1; ev1[0] = ej1; ev1[1] = ej1;
            f32x2 c;
            c[0] = __uint_as_float(u0.x << 16);
            c[1] = __uint_as_float(u0.x & 0xffff0000u);
            ac0[0] = __builtin_elementwise_fma(ev0, c, ac0[0]);
            c[0] = __uint_as_float(u0.y << 16);
            c[1] = __uint_as_float(u0.y & 0xffff0000u);
            ac0[1] = __builtin_elementwise_fma(ev0, c, ac0[1]);
            c[0] = __uint_as_float(u0.z << 16);
            c[1] = __uint_as_float(u0.z & 0xffff0000u);
            ac0[2] = __builtin_elementwise_fma(ev0, c, ac0[2]);
            c[0] = __uint_as_float(u0.w << 16);
            c[1] = __uint_as_float(u0.w & 0xffff0000u);
            ac0[3] = __builtin_elementwise_fma(ev0, c, ac0[3]);
            c[0] = __uint_as_float(u1.x << 16);
            c[1] = __uint_as_float(u1.x & 0xffff0000u);
            ac1[0] = __builtin_elementwise_fma(ev1, c, ac1[0]);
            c[0] = __uint_as_float(u1.y << 16);
            c[1] = __uint_as_float(u1.y & 0xffff0000u);
            ac1[1] = __builtin_elementwise_fma(ev1, c, ac1[1]);
            c[0] = __uint_as_float(u1.z << 16);
            c[1] = __uint_as_float(u1.z & 0xffff0000u);
            ac1[2] = __builtin_elementwise_fma(ev1, c, ac1[2]);
            c[0] = __uint_as_float(u1.w << 16);
            c[1] = __uint_as_float(u1.w & 0xffff0000u);
            ac1[3] = __builtin_elementwise_fma(ev1, c, ac1[3]);
        }
    }

    // stash partials to LDS, channel-major pad-9: addr = ch*9 + q with
    // ch = i8*8 + c. Write banks = bit-swap(lane) perm -> 2-way (free).
    float* r0 = &red[wave][0][0];
    float* r1 = &red[wave][1][0];
#pragma unroll
    for (int p = 0; p < 4; ++p) {
        r0[(i8 * 8 + 2 * p) * 9 + q]     = ac0[p][0];
        r0[(i8 * 8 + 2 * p + 1) * 9 + q] = ac0[p][1];
        r1[(i8 * 8 + 2 * p) * 9 + q]     = ac1[p][0];
        r1[(i8 * 8 + 2 * p + 1) * 9 + q] = ac1[p][1];
    }

    // psum reduce (overlaps LDS settle)
#pragma unroll
    for (int m2 = 32; m2 > 0; m2 >>= 1) {
        ps0 += __shfl_xor(ps0, m2, 64);
        ps1 += __shfl_xor(ps1, m2, 64);
    }

    const float2 asd = *(const float2*)(a_src + d0);
    float vs0 = asd.x + ad0;
    vs0 = vs0 > 0.f ? vs0 : NEG_SLOPE * vs0;
    const float es0 = __expf(vs0);
    const float inv0 = 1.f / (ps0 + es0);
    float es1 = 0.f, inv1 = 0.f;
    if (has1) {
        float vs1 = asd.y + ad1;
        vs1 = vs1 > 0.f ? vs1 : NEG_SLOPE * vs1;
        es1 = __expf(vs1);
        inv1 = 1.f / (ps1 + es1);
    }
    if (lane == 0) {
        adi[d0] = make_float2(ad0, inv0);
        if (has1) adi[d1] = make_float2(ad1, inv1);
    }

    // lane t owns channel ch == lane: sum its 8 q-partials
    float s0 = 0.f, s1 = 0.f;
#pragma unroll
    for (int qq = 0; qq < 8; ++qq) {
        s0 += r0[lane * 9 + qq];
        s1 += r1[lane * 9 + qq];
    }

    const ushort* hu = (const ushort*)h;
    const float bi = bias[lane];
    float hs0 = __uint_as_float(((unsigned)hu[(size_t)d0 * HID + lane]) << 16);
    out[(size_t)d0 * HID + lane] = fmaf(es0, hs0, s0) * inv0 + bi;
    if (has1) {
        float hs1 = __uint_as_float(((unsigned)hu[(size_t)d1 * HID + lane]) << 16);
        out[(size_t)d1 * HID + lane] = fmaf(es1, hs1, s1) * inv1 + bi;
    }
}

// ---------------------------------------------------------------------------
// edge-order alpha, vectorized 4-wide: int4 index loads, float4 stores.
// Self-loop entries (alpha[E..E+N)) handled as the tail thread range.
// ---------------------------------------------------------------------------
__global__ void k_alpha(const int* __restrict__ ei,
                        const float* __restrict__ a_src,
                        const float2* __restrict__ adi,
                        float* __restrict__ out_alpha, int E, int N)
{
    const int E4 = E >> 2;
    const int i = blockIdx.x * 256 + threadIdx.x;
    if (i < E4) {
        const int4 sv = ((const int4*)ei)[i];
        const int4 dv = ((const int4*)(ei + E))[i];
        float4 o;
        {
            const float2 av = adi[dv.x];
            float v = a_src[sv.x] + av.x;
            v = v > 0.f ? v : NEG_SLOPE * v;
            o.x = __expf(v) * av.y;
        }
        {
            const float2 av = adi[dv.y];
            float v = a_src[sv.y] + av.x;
            v = v > 0.f ? v : NEG_SLOPE * v;
            o.y = __expf(v) * av.y;
        }
        {
            const float2 av = adi[dv.z];
            float v = a_src[sv.z] + av.x;
            v = v > 0.f ? v : NEG_SLOPE * v;
            o.z = __expf(v) * av.y;
        }
        {
            const float2 av = adi[dv.w];
            float v = a_src[sv.w] + av.x;
            v = v > 0.f ? v : NEG_SLOPE * v;
            o.w = __expf(v) * av.y;
        }
        ((float4*)out_alpha)[i] = o;
    } else {
        const int j = i - E4;
        if (j < N) {
            const float2 av = adi[j];
            float v = a_src[j] + av.x;
            v = v > 0.f ? v : NEG_SLOPE * v;
            out_alpha[E + j] = __expf(v) * av.y;
        }
    }
}

// ---------------------------------------------------------------------------
extern "C" void kernel_launch(void* const* d_in, const int* in_sizes, int n_in,
                              void* d_out, int out_size, void* d_ws, size_t ws_size,
                              hipStream_t stream)
{
    (void)n_in; (void)out_size; (void)ws_size;
    const float* x       = (const float*)d_in[0];
    const int*   ei      = (const int*)d_in[1];
    const float* W       = (const float*)d_in[2];
    const float* att_src = (const float*)d_in[3];
    const float* att_dst = (const float*)d_in[4];
    const float* bias    = (const float*)d_in[5];

    const int N = in_sizes[0] / IN_CH;   // 100000
    const int E = in_sizes[1] / 2;       // 3200000
    const int nb = (N + 255) >> BSH;     // 391 buckets

    // workspace layout
    __hip_bfloat16* h = (__hip_bfloat16*)d_ws;     // N*HID bf16 (12.8 MB)
    float* a_src_d = (float*)(h + (size_t)N * HID);// N
    float* a_dst_d = a_src_d + N;                  // N
    float2* adi    = (float2*)(a_dst_d + N);       // N float2 (a_dst, inv_s)
    int* row_start = (int*)(adi + N);              // N
    int* cnt       = row_start + N;                // N
    int* g_cursor  = cnt + N;                      // 512
    short* wfrag   = (short*)(g_cursor + 512);     // 8192 shorts (16 KB)
    int* pairs     = (int*)(wfrag + 8192);         // nb*CAP
    int* csr_src   = pairs + (size_t)nb * CAP;     // E

    float* out       = (float*)d_out;              // N*HID
    float* out_alpha = out + (size_t)N * HID;      // E+N

    k_prep<<<4, 256, 0, stream>>>(W, wfrag, g_cursor);
    k_gemm<<<(N + 127) / 128, 256, 0, stream>>>(x, (const short8*)wfrag,
                                                att_src, att_dst,
                                                (short*)h, a_src_d, a_dst_d, N);
    k_binB<<<(E / 4 + 1023) / 1024, 512, 0, stream>>>(ei, g_cursor, pairs, E, nb);
    k_binC<<<nb, 512, 0, stream>>>(pairs, g_cursor,
                                   row_start, cnt, csr_src, N, nb);

    // k_agg split into two half-range dispatches (~32 us each): same total
    // work, same occupancy; keeps the rocprof top-5 visibility window open.
    const int H = 50000;                 // multiple of 8, = N/2
    k_agg<<<(H + 7) / 8, 256, 0, stream>>>(h, a_src_d, a_dst_d, bias,
                                           row_start, cnt, csr_src,
                                           out, adi, 0, H);
    k_agg<<<(N - H + 7) / 8, 256, 0, stream>>>(h, a_src_d, a_dst_d, bias,
                                               row_start, cnt, csr_src,
                                               out, adi, H, N);
    k_alpha<<<((E >> 2) + N + 255) / 256, 256, 0, stream>>>(ei, a_src_d, adi,
                                                            out_alpha, E, N);
}

// Round 10
// 248.534 us; speedup vs baseline: 1.3719x; 1.1100x over previous
//
#include <hip/hip_runtime.h>
#include <hip/hip_bf16.h>

#define IN_CH 128
#define HID 64
#define NEG_SLOPE 0.2f
#define BSH 8            // bucket = dst >> 8  (256 dsts per bucket)
#define CAP 10240        // per-bucket capacity (mean 8184, ~20-sigma slack)

typedef __attribute__((ext_vector_type(8))) short short8;   // bf16x8 frag (4 VGPRs)
typedef __attribute__((ext_vector_type(4))) float floatx4;  // fp32x4 acc
typedef __attribute__((ext_vector_type(2))) float f32x2;    // packed fma pair

__device__ inline short bfr(float f) {   // fp32 -> bf16 bits, round-nearest-even
    unsigned u = __float_as_uint(f);
    u += 0x7fffu + ((u >> 16) & 1u);
    return (short)(u >> 16);
}

// ---------------------------------------------------------------------------
// One-time: repack W (128x64 fp32) into bf16 MFMA B-fragments; block 0 also
// zeroes g_cursor (512 entries).
// ---------------------------------------------------------------------------
__global__ void k_prep(const float* __restrict__ W, short* __restrict__ wfrag,
                       int* __restrict__ g_cursor)
{
    if (blockIdx.x == 0) {
        g_cursor[threadIdx.x] = 0;
        g_cursor[threadIdx.x + 256] = 0;
    }
    int idx = blockIdx.x * 256 + threadIdx.x;
    if (idx >= 1024) return;
    int f = idx >> 6, l = idx & 63;
    int kt = f >> 2, nt = f & 3;
    int k0 = kt * 32 + (l >> 4) * 8;
    int n = nt * 16 + (l & 15);
#pragma unroll
    for (int j = 0; j < 8; ++j)
        wfrag[idx * 8 + j] = bfr(W[(k0 + j) * HID + n]);
}

// ---------------------------------------------------------------------------
// FUSED gemm + binB: data-independent kernels co-scheduled via blockIdx
// partition. binB blocks are latency-bound stall machines (VALU 3%, occ 22%
// measured r7); gemm's dense MFMA/VALU waves backfill those stall cycles.
//   blocks [0, GB):      gemm, 8 waves x 2 M-tiles = 256 rows/block
//   blocks [GB, GB+BB):  binB, 8 edges/thread, rank captured in count pass
// BB MUST be ceil((E/4)/1024) = 782 — r9's E/4096 dropped the last 4096
// edges (correctness failure, absmax 1.99).
// C-layout: col = lane&15, row = quad*4 + reg  [m89].
// ---------------------------------------------------------------------------
__global__ __launch_bounds__(512, 2) void k_gb(
    const float* __restrict__ x, const short8* __restrict__ wfrag,
    const float* __restrict__ att_src, const float* __restrict__ att_dst,
    short* __restrict__ h, float* __restrict__ a_src,
    float* __restrict__ a_dst,
    const int* __restrict__ ei, int* __restrict__ g_cursor,
    int* __restrict__ pairs, int E, int N, int nb, int GB)
{
    __shared__ int hist[512];
    __shared__ int base[512];

    const int t = threadIdx.x;

    if ((int)blockIdx.x < GB) {
        // ---------------- gemm path ----------------
        const int lane = t & 63;
        const int wv = t >> 6;            // 8 waves
        const int l15 = lane & 15;
        const int quad = lane >> 4;

        short8 bf[16];
#pragma unroll
        for (int f = 0; f < 16; ++f) bf[f] = wfrag[f * 64 + lane];

        float as4[4], ad4[4];
#pragma unroll
        for (int nt = 0; nt < 4; ++nt) {
            as4[nt] = att_src[nt * 16 + l15];
            ad4[nt] = att_dst[nt * 16 + l15];
        }

        const int rowbase = blockIdx.x * 256 + wv * 32;

#pragma unroll
        for (int mt = 0; mt < 2; ++mt) {
            const int m0 = rowbase + mt * 16;
            const int rowa = m0 + l15;
            const int rowc = rowa < N ? rowa : N - 1;   // clamp loads
            const float* xp = x + (size_t)rowc * IN_CH + quad * 8;

            short8 af[4];
#pragma unroll
            for (int kt = 0; kt < 4; ++kt) {
                float4 p0 = *(const float4*)(xp + kt * 32);
                float4 p1 = *(const float4*)(xp + kt * 32 + 4);
                short8 a;
                a[0] = bfr(p0.x); a[1] = bfr(p0.y); a[2] = bfr(p0.z); a[3] = bfr(p0.w);
                a[4] = bfr(p1.x); a[5] = bfr(p1.y); a[6] = bfr(p1.z); a[7] = bfr(p1.w);
                af[kt] = a;
            }

            floatx4 acc[4];
#pragma unroll
            for (int nt = 0; nt < 4; ++nt) acc[nt] = (floatx4){0.f, 0.f, 0.f, 0.f};
#pragma unroll
            for (int kt = 0; kt < 4; ++kt)
#pragma unroll
                for (int nt = 0; nt < 4; ++nt)
                    acc[nt] = __builtin_amdgcn_mfma_f32_16x16x32_bf16(
                        af[kt], bf[kt * 4 + nt], acc[nt], 0, 0, 0);

            // epilogue: rows m0 + quad*4 + r
#pragma unroll
            for (int r = 0; r < 4; ++r) {
                const int row = m0 + quad * 4 + r;
                const bool ok = row < N;
                if (ok) {
#pragma unroll
                    for (int nt = 0; nt < 4; ++nt)
                        h[(size_t)row * HID + nt * 16 + l15] = bfr(acc[nt][r]);
                }
                float ps = acc[0][r] * as4[0] + acc[1][r] * as4[1] +
                           acc[2][r] * as4[2] + acc[3][r] * as4[3];
                float pd = acc[0][r] * ad4[0] + acc[1][r] * ad4[1] +
                           acc[2][r] * ad4[2] + acc[3][r] * ad4[3];
#pragma unroll
                for (int m2 = 1; m2 < 16; m2 <<= 1) {
                    ps += __shfl_xor(ps, m2, 64);
                    pd += __shfl_xor(pd, m2, 64);
                }
                if (ok && l15 == 0) { a_src[row] = ps; a_dst[row] = pd; }
            }
        }
    } else {
        // ---------------- binB path ----------------
        const int bb = blockIdx.x - GB;
        hist[t] = 0;
        __syncthreads();

        int s[8], d[8], l[8];
        const int4* s4 = (const int4*)ei;
        const int4* d4 = (const int4*)(ei + E);
        const int E4 = E >> 2;
        const int q0 = bb * 1024;
#pragma unroll
        for (int i = 0; i < 2; ++i) {
            int q = q0 + i * 512 + t;
            int4 sv = make_int4(0, 0, 0, 0);
            int4 dv = make_int4(-1, -1, -1, -1);
            if (q < E4) { sv = s4[q]; dv = d4[q]; }
            s[4 * i + 0] = sv.x; s[4 * i + 1] = sv.y; s[4 * i + 2] = sv.z; s[4 * i + 3] = sv.w;
            d[4 * i + 0] = dv.x; d[4 * i + 1] = dv.y; d[4 * i + 2] = dv.z; d[4 * i + 3] = dv.w;
        }
#pragma unroll
        for (int i = 0; i < 8; ++i)
            if (d[i] >= 0) l[i] = atomicAdd(&hist[d[i] >> BSH], 1);
        __syncthreads();

        if (t < nb) base[t] = atomicAdd(&g_cursor[t], hist[t]);
        __syncthreads();

#pragma unroll
        for (int i = 0; i < 8; ++i) {
            if (d[i] < 0) continue;
            int b = d[i] >> BSH;
            int pos = base[b] + l[i];
            if (pos < CAP)
                pairs[b * CAP + pos] = s[i] | ((d[i] & 255) << 17);
        }
    }
}

// ---------------------------------------------------------------------------
// Per-bucket finalize: one block (512 thr) per 256-dst bucket. Two-pass over
// the bucket window with INT4 reads. In-block redundant scan of bucket counts
// -> base; LDS per-dst hist -> scan -> row_start/cnt -> scatter csr.
// ---------------------------------------------------------------------------
__global__ __launch_bounds__(512) void k_binC(
    const int* __restrict__ pairs, const int* __restrict__ g_cursor,
    int* __restrict__ row_start, int* __restrict__ cnt,
    int* __restrict__ csr_src, int N, int nb)
{
    __shared__ int h0[256];
    __shared__ int hs[512];
    __shared__ int cur[256];
    __shared__ int sbase;
    const int t = threadIdx.x;
    const int b = blockIdx.x;
    int m = g_cursor[b];
    if (m > CAP) m = CAP;
    const int4* pb4 = (const int4*)(pairs + b * CAP);
    const int m4 = (m + 3) >> 2;

    // exclusive bucket-base via redundant in-block scan over nb (<512) entries
    int bv = (t < nb) ? g_cursor[t] : 0;
    hs[t] = bv;
    __syncthreads();
    for (int off = 1; off < 512; off <<= 1) {
        int u = (t >= off) ? hs[t - off] : 0;
        __syncthreads();
        hs[t] += u;
        __syncthreads();
    }
    if (t == b) sbase = hs[t] - bv;
    if (t < 256) h0[t] = 0;
    __syncthreads();
    const int basec = sbase;

    for (int i4 = t; i4 < m4; i4 += 512) {
        const int4 p = pb4[i4];
        const int i = i4 << 2;
        if (i + 3 < m) {
            atomicAdd(&h0[p.x >> 17], 1);
            atomicAdd(&h0[p.y >> 17], 1);
            atomicAdd(&h0[p.z >> 17], 1);
            atomicAdd(&h0[p.w >> 17], 1);
        } else {
            if (i     < m) atomicAdd(&h0[p.x >> 17], 1);
            if (i + 1 < m) atomicAdd(&h0[p.y >> 17], 1);
            if (i + 2 < m) atomicAdd(&h0[p.z >> 17], 1);
        }
    }
    __syncthreads();

    // scan the 256 per-dst counts (guarded; barriers stay uniform)
    if (t < 256) hs[t] = h0[t];
    __syncthreads();
    for (int off = 1; off < 256; off <<= 1) {
        int u = (t >= off && t < 256) ? hs[t - off] : 0;
        __syncthreads();
        if (t < 256) hs[t] += u;
        __syncthreads();
    }
    if (t < 256) {
        const int excl = hs[t] - h0[t];
        cur[t] = basec + excl;
        const int dd = (b << BSH) + t;
        if (dd < N) { row_start[dd] = basec + excl; cnt[dd] = h0[t]; }
    }
    __syncthreads();

    for (int i4 = t; i4 < m4; i4 += 512) {
        const int4 p = pb4[i4];
        const int i = i4 << 2;
        if (i < m) {
            int pos = atomicAdd(&cur[p.x >> 17], 1);
            csr_src[pos] = p.x & 0x1FFFF;
        }
        if (i + 1 < m) {
            int pos = atomicAdd(&cur[p.y >> 17], 1);
            csr_src[pos] = p.y & 0x1FFFF;
        }
        if (i + 2 < m) {
            int pos = atomicAdd(&cur[p.z >> 17], 1);
            csr_src[pos] = p.z & 0x1FFFF;
        }
        if (i + 3 < m) {
            int pos = atomicAdd(&cur[p.w >> 17], 1);
            csr_src[pos] = p.w & 0x1FFFF;
        }
    }
}

// ---------------------------------------------------------------------------
// Aggregation: two dsts per wave, interleaved (proven 63 us form, inner loop
// byte-identical). Single dispatch.
// ---------------------------------------------------------------------------
__global__ __launch_bounds__(256) void k_agg(
    const __hip_bfloat16* __restrict__ h, const float* __restrict__ a_src,
    const float* __restrict__ a_dst, const float* __restrict__ bias,
    const int* __restrict__ row_start, const int* __restrict__ cnt,
    const int* __restrict__ csr_src,
    float* __restrict__ out, float2* __restrict__ adi, int N)
{
    __shared__ float red[4][2][576];   // [wave][dst][ch*9+q], pad 9

    const int wave = threadIdx.x >> 6;
    const int lane = threadIdx.x & 63;
    const int d0 = blockIdx.x * 8 + wave * 2;
    if (d0 >= N) return;
    const int d1 = d0 + 1;
    const bool has1 = d1 < N;

    const int q  = lane >> 3;   // row slot within group of 8
    const int i8 = lane & 7;    // 16-B chunk of the 128-B row

    const float2 ad2 = *(const float2*)(a_dst + d0);   // d0 even
    const float ad0 = ad2.x;
    const float ad1 = ad2.y;
    const int2 cn2 = *(const int2*)(cnt + d0);
    const int n0 = cn2.x;
    const int n1 = has1 ? cn2.y : 0;
    const int st0 = row_start[d0];
    const int en0 = st0 + n0;
    const int st1 = en0;                 // CSR globally contiguous
    const int en1 = st1 + n1;

    const uint4* h4 = (const uint4*)h;

    float ps0 = 0.f, ps1 = 0.f;
    f32x2 ac0[4], ac1[4];
#pragma unroll
    for (int c = 0; c < 4; ++c) {
        ac0[c] = (f32x2){0.f, 0.f};
        ac1[c] = (f32x2){0.f, 0.f};
    }

    const int nbt0 = (n0 + 63) >> 6;
    const int nbt1 = (n1 + 63) >> 6;
    const int nbm = nbt0 > nbt1 ? nbt0 : nbt1;

    int b0 = st0, b1 = st1;
    for (int it = 0; it < nbm; ++it, b0 += 64, b1 += 64) {
        int s0v = 0, s1v = 0;
        float e0 = 0.f, e1 = 0.f;
        const int idx0 = b0 + lane;
        if (it < nbt0 && idx0 < en0) {
            s0v = csr_src[idx0];
            float v = a_src[s0v] + ad0;
            v = v > 0.f ? v : NEG_SLOPE * v;
            e0 = __expf(v);
            ps0 += e0;
        }
        const int idx1 = b1 + lane;
        if (it < nbt1 && idx1 < en1) {
            s1v = csr_src[idx1];
            float v = a_src[s1v] + ad1;
            v = v > 0.f ? v : NEG_SLOPE * v;
            e1 = __expf(v);
            ps1 += e1;
        }
        const int m0 = (it < nbt0) ? min(64, en0 - b0) : 0;
        const int m1 = (it < nbt1) ? min(64, en1 - b1) : 0;
        const int mm = m0 > m1 ? m0 : m1;
#pragma unroll 4
        for (int j = 0; j < mm; j += 8) {
            const int jq = j + q;
            const int sj0 = __shfl(s0v, jq, 64);    // inactive slots: s=0,e=0
            const float ej0 = __shfl(e0, jq, 64);   // -> harmless row-0 load
            const int sj1 = __shfl(s1v, jq, 64);
            const float ej1 = __shfl(e1, jq, 64);
            uint4 u0 = h4[(size_t)sj0 * 8 + i8];
            uint4 u1 = h4[(size_t)sj1 * 8 + i8];
            f32x2 ev0; ev0[0] = ej0; ev0[1] = ej0;
            f32x2 ev1; ev1[0] = ej1; ev1[1] = ej1;
            f32x2 c;
            c[0] = __uint_as_float(u0.x << 16);
            c[1] = __uint_as_float(u0.x & 0xffff0000u);
            ac0[0] = __builtin_elementwise_fma(ev0, c, ac0[0]);
            c[0] = __uint_as_float(u0.y << 16);
            c[1] = __uint_as_float(u0.y & 0xffff0000u);
            ac0[1] = __builtin_elementwise_fma(ev0, c, ac0[1]);
            c[0] = __uint_as_float(u0.z << 16);
            c[1] = __uint_as_float(u0.z & 0xffff0000u);
            ac0[2] = __builtin_elementwise_fma(ev0, c, ac0[2]);
            c[0] = __uint_as_float(u0.w << 16);
            c[1] = __uint_as_float(u0.w & 0xffff0000u);
            ac0[3] = __builtin_elementwise_fma(ev0, c, ac0[3]);
            c[0] = __uint_as_float(u1.x << 16);
            c[1] = __uint_as_float(u1.x & 0xffff0000u);
            ac1[0] = __builtin_elementwise_fma(ev1, c, ac1[0]);
            c[0] = __uint_as_float(u1.y << 16);
            c[1] = __uint_as_float(u1.y & 0xffff0000u);
            ac1[1] = __builtin_elementwise_fma(ev1, c, ac1[1]);
            c[0] = __uint_as_float(u1.z << 16);
            c[1] = __uint_as_float(u1.z & 0xffff0000u);
            ac1[2] = __builtin_elementwise_fma(ev1, c, ac1[2]);
            c[0] = __uint_as_float(u1.w << 16);
            c[1] = __uint_as_float(u1.w & 0xffff0000u);
            ac1[3] = __builtin_elementwise_fma(ev1, c, ac1[3]);
        }
    }

    // stash partials to LDS, channel-major pad-9: addr = ch*9 + q with
    // ch = i8*8 + c. Write banks = bit-swap(lane) perm -> 2-way (free).
    float* r0 = &red[wave][0][0];
    float* r1 = &red[wave][1][0];
#pragma unroll
    for (int p = 0; p < 4; ++p) {
        r0[(i8 * 8 + 2 * p) * 9 + q]     = ac0[p][0];
        r0[(i8 * 8 + 2 * p + 1) * 9 + q] = ac0[p][1];
        r1[(i8 * 8 + 2 * p) * 9 + q]     = ac1[p][0];
        r1[(i8 * 8 + 2 * p + 1) * 9 + q] = ac1[p][1];
    }

    // psum reduce (overlaps LDS settle)
#pragma unroll
    for (int m2 = 32; m2 > 0; m2 >>= 1) {
        ps0 += __shfl_xor(ps0, m2, 64);
        ps1 += __shfl_xor(ps1, m2, 64);
    }

    const float2 asd = *(const float2*)(a_src + d0);
    float vs0 = asd.x + ad0;
    vs0 = vs0 > 0.f ? vs0 : NEG_SLOPE * vs0;
    const float es0 = __expf(vs0);
    const float inv0 = 1.f / (ps0 + es0);
    float es1 = 0.f, inv1 = 0.f;
    if (has1) {
        float vs1 = asd.y + ad1;
        vs1 = vs1 > 0.f ? vs1 : NEG_SLOPE * vs1;
        es1 = __expf(vs1);
        inv1 = 1.f / (ps1 + es1);
    }
    if (lane == 0) {
        adi[d0] = make_float2(ad0, inv0);
        if (has1) adi[d1] = make_float2(ad1, inv1);
    }

    // lane t owns channel ch == lane: sum its 8 q-partials
    float s0 = 0.f, s1 = 0.f;
#pragma unroll
    for (int qq = 0; qq < 8; ++qq) {
        s0 += r0[lane * 9 + qq];
        s1 += r1[lane * 9 + qq];
    }

    const ushort* hu = (const ushort*)h;
    const float bi = bias[lane];
    float hs0 = __uint_as_float(((unsigned)hu[(size_t)d0 * HID + lane]) << 16);
    out[(size_t)d0 * HID + lane] = fmaf(es0, hs0, s0) * inv0 + bi;
    if (has1) {
        float hs1 = __uint_as_float(((unsigned)hu[(size_t)d1 * HID + lane]) << 16);
        out[(size_t)d1 * HID + lane] = fmaf(es1, hs1, s1) * inv1 + bi;
    }
}

// ---------------------------------------------------------------------------
// edge-order alpha, vectorized 4-wide: int4 index loads, float4 stores.
// Self-loop entries (alpha[E..E+N)) handled as the tail thread range.
// ---------------------------------------------------------------------------
__global__ void k_alpha(const int* __restrict__ ei,
                        const float* __restrict__ a_src,
                        const float2* __restrict__ adi,
                        float* __restrict__ out_alpha, int E, int N)
{
    const int E4 = E >> 2;
    const int i = blockIdx.x * 256 + threadIdx.x;
    if (i < E4) {
        const int4 sv = ((const int4*)ei)[i];
        const int4 dv = ((const int4*)(ei + E))[i];
        float4 o;
        {
            const float2 av = adi[dv.x];
            float v = a_src[sv.x] + av.x;
            v = v > 0.f ? v : NEG_SLOPE * v;
            o.x = __expf(v) * av.y;
        }
        {
            const float2 av = adi[dv.y];
            float v = a_src[sv.y] + av.x;
            v = v > 0.f ? v : NEG_SLOPE * v;
            o.y = __expf(v) * av.y;
        }
        {
            const float2 av = adi[dv.z];
            float v = a_src[sv.z] + av.x;
            v = v > 0.f ? v : NEG_SLOPE * v;
            o.z = __expf(v) * av.y;
        }
        {
            const float2 av = adi[dv.w];
            float v = a_src[sv.w] + av.x;
            v = v > 0.f ? v : NEG_SLOPE * v;
            o.w = __expf(v) * av.y;
        }
        ((float4*)out_alpha)[i] = o;
    } else {
        const int j = i - E4;
        if (j < N) {
            const float2 av = adi[j];
            float v = a_src[j] + av.x;
            v = v > 0.f ? v : NEG_SLOPE * v;
            out_alpha[E + j] = __expf(v) * av.y;
        }
    }
}

// ---------------------------------------------------------------------------
extern "C" void kernel_launch(void* const* d_in, const int* in_sizes, int n_in,
                              void* d_out, int out_size, void* d_ws, size_t ws_size,
                              hipStream_t stream)
{
    (void)n_in; (void)out_size; (void)ws_size;
    const float* x       = (const float*)d_in[0];
    const int*   ei      = (const int*)d_in[1];
    const float* W       = (const float*)d_in[2];
    const float* att_src = (const float*)d_in[3];
    const float* att_dst = (const float*)d_in[4];
    const float* bias    = (const float*)d_in[5];

    const int N = in_sizes[0] / IN_CH;   // 100000
    const int E = in_sizes[1] / 2;       // 3200000
    const int nb = (N + 255) >> BSH;     // 391 buckets

    // workspace layout
    __hip_bfloat16* h = (__hip_bfloat16*)d_ws;     // N*HID bf16 (12.8 MB)
    float* a_src_d = (float*)(h + (size_t)N * HID);// N
    float* a_dst_d = a_src_d + N;                  // N
    float2* adi    = (float2*)(a_dst_d + N);       // N float2 (a_dst, inv_s)
    int* row_start = (int*)(adi + N);              // N
    int* cnt       = row_start + N;                // N
    int* g_cursor  = cnt + N;                      // 512
    short* wfrag   = (short*)(g_cursor + 512);     // 8192 shorts (16 KB)
    int* pairs     = (int*)(wfrag + 8192);         // nb*CAP
    int* csr_src   = pairs + (size_t)nb * CAP;     // E

    float* out       = (float*)d_out;              // N*HID
    float* out_alpha = out + (size_t)N * HID;      // E+N

    const int GB = (N + 255) / 256;                // 391 gemm blocks
    const int BB = (E / 4 + 1023) / 1024;          // 782 binB blocks (ceil!)

    k_prep<<<4, 256, 0, stream>>>(W, wfrag, g_cursor);
    k_gb<<<GB + BB, 512, 0, stream>>>(x, (const short8*)wfrag,
                                      att_src, att_dst,
                                      (short*)h, a_src_d, a_dst_d,
                                      ei, g_cursor, pairs, E, N, nb, GB);
    k_binC<<<nb, 512, 0, stream>>>(pairs, g_cursor,
                                   row_start, cnt, csr_src, N, nb);
    k_agg<<<(N + 7) / 8, 256, 0, stream>>>(h, a_src_d, a_dst_d, bias,
                                           row_start, cnt, csr_src,
                                           out, adi, N);
    k_alpha<<<((E >> 2) + N + 255) / 256, 256, 0, stream>>>(ei, a_src_d, adi,
                                                            out_alpha, E, N);
}